// Round 16
// baseline (176.797 us; speedup 1.0000x reference)
//
#include <hip/hip_runtime.h>
#include <hip/hip_bf16.h>
#include <stdint.h>

typedef __hip_bfloat16 bf16;
typedef unsigned short u16;
typedef __attribute__((ext_vector_type(8))) short short8;
typedef __attribute__((ext_vector_type(4))) float f32x4;
typedef __attribute__((ext_vector_type(16))) float f32x16;
typedef __attribute__((ext_vector_type(4))) int int4v;

#define BATCH 8
#define SEQ   1024
#define DIM   1024
#define NHEAD 16
#define HD    64
#define SCALE 0.03125f               // DIM^-0.5 = 1/32 (exact)
#define C2    0.04508422f            // SCALE * log2(e)

static __device__ __forceinline__ f32x4 mfma_bf16(short8 a, short8 b, f32x4 c) {
    return __builtin_amdgcn_mfma_f32_16x16x32_bf16(a, b, c, 0, 0, 0);
}
static __device__ __forceinline__ f32x16 mfma32(short8 a, short8 b, f32x16 c) {
    return __builtin_amdgcn_mfma_f32_32x32x16_bf16(a, b, c, 0, 0, 0);
}
static __device__ __forceinline__ unsigned cvt_pk_bf16(float lo, float hi) {
    unsigned r;
    asm("v_cvt_pk_bf16_f32 %0, %1, %2" : "=v"(r) : "v"(lo), "v"(hi));
    return r;
}
// async global->LDS, 16B per lane; LDS dest = wave-uniform base + lane*16
static __device__ __forceinline__ void gload16(const u16* g, u16* l) {
    __builtin_amdgcn_global_load_lds(
        (const __attribute__((address_space(1))) void*)g,
        (__attribute__((address_space(3))) void*)l, 16, 0, 0);
}

// ---------------------------------------------------------------------------
// Fused preprocessing: dtype detect (per-block, from bit patterns) +
// all 4 float-tensor conversions + mask expansion in ONE launch.
// ---------------------------------------------------------------------------
static __device__ __forceinline__ void conv_seg(const void* src, u16* dst,
                                                int total, int bloc, int bcnt,
                                                bool f32in)
{
    for (int i = bloc * 256 + (int)threadIdx.x; i < total; i += bcnt * 256) {
        if (f32in) {
            const float4 a = ((const float4*)src)[2 * i];
            const float4 b = ((const float4*)src)[2 * i + 1];
            short8 o;
            o[0] = (short)__builtin_bit_cast(u16, __float2bfloat16(a.x));
            o[1] = (short)__builtin_bit_cast(u16, __float2bfloat16(a.y));
            o[2] = (short)__builtin_bit_cast(u16, __float2bfloat16(a.z));
            o[3] = (short)__builtin_bit_cast(u16, __float2bfloat16(a.w));
            o[4] = (short)__builtin_bit_cast(u16, __float2bfloat16(b.x));
            o[5] = (short)__builtin_bit_cast(u16, __float2bfloat16(b.y));
            o[6] = (short)__builtin_bit_cast(u16, __float2bfloat16(b.z));
            o[7] = (short)__builtin_bit_cast(u16, __float2bfloat16(b.w));
            ((short8*)dst)[i] = o;
        } else {
            ((short8*)dst)[i] = ((const short8*)src)[i];
        }
    }
}

__global__ __launch_bounds__(256)
void prep_all(const void* __restrict__ x, const void* __restrict__ mask,
              const void* __restrict__ wq, const void* __restrict__ wo,
              const void* __restrict__ bo,
              u16* __restrict__ xb, u16* __restrict__ wqb,
              u16* __restrict__ wob, u16* __restrict__ bob,
              unsigned long long* __restrict__ mask64)
{
    __shared__ int s_cnt[2];
    if (threadIdx.x == 0) { s_cnt[0] = 0; s_cnt[1] = 0; }
    __syncthreads();
    {
        const uint32_t wx = ((const uint32_t*)x)[threadIdx.x];
        const int e = (int)((wx >> 7) & 0xFFu);
        if (e >= 96 && e <= 159) atomicAdd(&s_cnt[0], 1);
        const uint32_t wm = ((const uint32_t*)mask)[threadIdx.x];
        if (wm > 1u) atomicAdd(&s_cnt[1], 1);
    }
    __syncthreads();
    const bool f32in = (s_cnt[0] < 192);
    const bool mbyte = (s_cnt[1] > 0);

    const int bid = blockIdx.x;
    if (bid < 2048)       conv_seg(x,  xb,  1048576, bid,        2048, f32in);
    else if (bid < 2816)  conv_seg(wq, wqb, 393216,  bid - 2048,  768, f32in);
    else if (bid < 3072)  conv_seg(wo, wob, 131072,  bid - 2816,  256, f32in);
    else if (bid == 3072) conv_seg(bo, bob, 128,     0,             1, f32in);
    else {
        const int b = bid - 3073;          // 0..7
#pragma unroll
        for (int c = 0; c < 4; ++c) {
            const int i = c * 256 + (int)threadIdx.x;
            int v;
            if (i == 0) v = 1;
            else if (mbyte) v = (int)((const uint8_t*)mask)[b * (SEQ - 1) + i - 1];
            else            v = ((const int*)mask)[b * (SEQ - 1) + i - 1];
            v = v ? 1 : 0;
            const unsigned long long bal = __ballot(v);
            if ((i & 63) == 0) mask64[b * 16 + (i >> 6)] = bal;
        }
    }
}

// ---------------------------------------------------------------------------
// GEMM: C = A @ B^T, K=1024, bf16. Round-16 geometry: block tile 128x256,
// 4 waves (2Mx2N), per-wave 64x128 (acc[4][8]) -> 0.75x LDS traffic/FLOP.
// BK=64, 8 phases/K-tile (one B-nt per phase), B-reads pipelined one phase
// ahead with counted lgkmcnt(2); stages (12 gload_lds) spread 2/phase over
// phases 0-5; single vmcnt(0)+barrier per K-tile. LDS 96KB, 1 block/CU.
// Source-side XOR swizzle identical to round-11 (measured 0 conflicts).
// EPI 0: scatter q(xC2)/k/v^T.  EPI 1: C + bias -> f32.
// ---------------------------------------------------------------------------
template<int EPI>
__global__ __launch_bounds__(256, 1)
void gemm_bt(const u16* __restrict__ A, const u16* __restrict__ Bm,
             bf16* __restrict__ o0, bf16* __restrict__ o1, bf16* __restrict__ o2,
             float* __restrict__ fo, const u16* __restrict__ bias)
{
    constexpr int K   = 1024;
    constexpr int NT  = K / 64;          // 16 K-tiles
    constexpr int BUF = 384 * 64;        // u16 per buffer (48KB)
    __shared__ u16 lds[2 * BUF];         // 96KB total

    const int tid  = threadIdx.x;
    const int lane = tid & 63;
    const int w    = tid >> 6;           // 0..3
    const int wr   = w >> 1, wc = w & 1; // 2M x 2N waves, wave = 64x128
    const int l15  = lane & 15, l4 = lane >> 4;

    const long atile = (long)blockIdx.x * 128;
    const long btile = (long)blockIdx.y * 256;

    // staging: 48 chunks of 8 rows x 64 cols (1KB each); wave w owns
    // chunks 12w..12w+11. lane -> row chunk*8 + (lane>>3), LDS slot lane&7,
    // global col-chunk (lane&7)^(lane>>3)  [LDS[r][s] = G[r][s^(r&7)]].
    const int rl  = lane >> 3;
    const int gs8 = ((lane & 7) ^ rl) * 8;
    const u16* gp[12];
#pragma unroll
    for (int j = 0; j < 12; ++j) {
        const int g = 12 * w + j;
        const int r = g * 8 + rl;        // combined row: [0,128)=A, [128,384)=B
        gp[j] = (r < 128) ? A  + (atile + r) * (long)K + gs8
                          : Bm + (btile + (r - 128)) * (long)K + gs8;
    }

    // read map (round-11 proven): slot = ((kk^b2)*4 + (l4^(l15&3)))*8
    const int lx  = l4 ^ (l15 & 3);
    const int b2  = (l15 >> 2) & 1;
    const int sl0 = (b2 * 4 + lx) * 8;          // kk=0
    const int sl1 = (((1 ^ b2) * 4) + lx) * 8;  // kk=1
    const int ar  = wr * 64 + l15;              // + mt*16
    const int br  = 128 + wc * 128 + l15;       // + nt*16

    f32x4 acc[4][8];
    const f32x4 fz = {0.f, 0.f, 0.f, 0.f};
#pragma unroll
    for (int i = 0; i < 4; ++i)
#pragma unroll
        for (int j = 0; j < 8; ++j) acc[i][j] = fz;

#define STG(bufo, kt, j) gload16(gp[j] + (size_t)(kt) * 64, \
                                 &lds[(bufo) + (12 * w + (j)) * 512])

    // prologue: stage tile 0
#pragma unroll
    for (int j = 0; j < 12; ++j) STG(0, 0, j);
    asm volatile("s_waitcnt vmcnt(0)" ::: "memory");
    __builtin_amdgcn_s_barrier();
    __builtin_amdgcn_sched_barrier(0);

    int cur = 0;
#pragma unroll 1
    for (int kt = 0; kt < NT; ++kt) {
        const int co = cur * BUF;
        const int no = (cur ^ 1) * BUF;
        const bool st = (kt + 1 < NT);

        // pre-reads: all A-frags (8) + B[0] (2)
        short8 af[4][2];
#pragma unroll
        for (int mt = 0; mt < 4; ++mt) {
            af[mt][0] = *(const short8*)&lds[co + (ar + mt * 16) * 64 + sl0];
            af[mt][1] = *(const short8*)&lds[co + (ar + mt * 16) * 64 + sl1];
        }
        short8 bc0 = *(const short8*)&lds[co + br * 64 + sl0];
        short8 bc1 = *(const short8*)&lds[co + br * 64 + sl1];

#pragma unroll
        for (int p = 0; p < 8; ++p) {
            short8 bn0, bn1;
            if (p < 7) {               // pipeline B[p+1] under phase p's MFMA
                bn0 = *(const short8*)&lds[co + (br + (p + 1) * 16) * 64 + sl0];
                bn1 = *(const short8*)&lds[co + (br + (p + 1) * 16) * 64 + sl1];
            }
            if (p < 6 && st) { STG(no, kt + 1, 2 * p); STG(no, kt + 1, 2 * p + 1); }
            if (p < 7) asm volatile("s_waitcnt lgkmcnt(2)" ::: "memory");
            else       asm volatile("s_waitcnt lgkmcnt(0)" ::: "memory");
            __builtin_amdgcn_sched_barrier(0);     // rule #18 fence
#pragma unroll
            for (int kk = 0; kk < 2; ++kk)
#pragma unroll
                for (int mt = 0; mt < 4; ++mt)
                    acc[mt][p] = mfma_bf16(af[mt][kk], kk ? bc1 : bc0, acc[mt][p]);
            if (p < 7) { bc0 = bn0; bc1 = bn1; }
        }

        asm volatile("s_waitcnt vmcnt(0)" ::: "memory");
        __builtin_amdgcn_s_barrier();
        __builtin_amdgcn_sched_barrier(0);
        cur ^= 1;
    }
#undef STG

    // epilogue: C/D layout col = lane&15, row = (lane>>4)*4 + r  [m89/m91]
    const long ci0 = atile + wr * 64;
    const int  cj0 = (int)btile + wc * 128;
#pragma unroll
    for (int mt = 0; mt < 4; ++mt) {
#pragma unroll
        for (int nt = 0; nt < 8; ++nt) {
            const int j = cj0 + nt * 16 + l15;
#pragma unroll
            for (int r = 0; r < 4; ++r) {
                const long i = ci0 + mt * 16 + l4 * 4 + r;
                float vv = acc[mt][nt][r];
                if (EPI == 0) {
                    const int which = j >> 10;         // 0=q 1=k 2=v
                    const int h     = (j >> 6) & 15;
                    const int dd    = j & 63;
                    const long b    = i >> 10;
                    const long n    = i & 1023;
                    const long bhh  = b * NHEAD + h;
                    if (which == 0)  // Q pre-scaled by C2 (softmax fold)
                        o0[(bhh * SEQ + n) * HD + dd] = __float2bfloat16(vv * C2);
                    else if (which == 1)
                        o1[(bhh * SEQ + n) * HD + dd] = __float2bfloat16(vv);
                    else // V stored transposed: [bh][d][n]
                        o2[(bhh * HD + dd) * SEQ + n] = __float2bfloat16(vv);
                } else {
                    const u16 bw = bias[j];
                    vv += __bfloat162float(__builtin_bit_cast(bf16, bw));
                    fo[i * DIM + j] = vv;
                }
            }
        }
    }
}

// ---------------------------------------------------------------------------
// Flash attention, swapped-operand 32x32 form (unchanged from round 15).
// ---------------------------------------------------------------------------
__global__ __launch_bounds__(256)
void attn_fwd(const bf16* __restrict__ q, const bf16* __restrict__ k,
              const bf16* __restrict__ vt_g,
              const unsigned long long* __restrict__ mask64,
              bf16* __restrict__ o)
{
    __shared__ u16 kl[2][64 * 72];     // K tile  [k in tile][d], +8 pad
    __shared__ u16 vl[2][64 * 72];     // V^T tile [d][k in tile], +8 pad

    const int tid  = threadIdx.x;
    const int lane = tid & 63;
    const int w    = tid >> 6;
    const int l31  = lane & 31;
    const int hi   = lane >> 5;
    const int bh   = blockIdx.x >> 3;
    const int qt   = blockIdx.x & 7;
    const int b    = bh >> 4;
    const int h    = bh & 15;

    const long base  = (long)bh * SEQ * HD;   // q,k: [bh][n][64]
    const long vbase = (long)bh * HD * SEQ;   // v^T: [bh][d][1024]

    const int qrow = qt * 128 + w * 32 + l31;
    const int mi   = (int)((mask64[b * 16 + (qrow >> 6)] >> (qrow & 63)) & 1ull);

    short8 qf[4];
#pragma unroll
    for (int s4 = 0; s4 < 4; ++s4)
        qf[s4] = *(const short8*)(q + base + (long)qrow * HD + s4 * 16 + hi * 8);
    if (!mi) {                         // dead q-row: zero Q -> s == 0
#pragma unroll
        for (int s4 = 0; s4 < 4; ++s4)
            qf[s4] = __builtin_bit_cast(short8, (int4v){0, 0, 0, 0});
    }

    f32x16 oacc0, oacc1, oaccS, zc;
#pragma unroll
    for (int i = 0; i < 16; ++i)
        { oacc0[i] = 0.f; oacc1[i] = 0.f; oaccS[i] = 0.f; zc[i] = 0.f; }

    const u16 NEGW = __builtin_bit_cast(u16, __float2bfloat16(-1e30f));
    const short8 vfB = __builtin_bit_cast(short8,  // bias gate: mi(q) at kk=0
        (int4v){(hi == 0 && mi) ? 0x3F80 : 0, 0, 0, 0});
    const short8 vfS = __builtin_bit_cast(short8,  // all-ones column (row sum)
        (int4v){0x3F803F80, 0x3F803F80, 0x3F803F80, 0x3F803F80});

    const int sr = tid >> 2, sc = tid & 3;
    short8 rk0 = *(const short8*)(k + base + (long)sr * HD + sc * 8);
    short8 rk1 = *(const short8*)(k + base + (long)sr * HD + 32 + sc * 8);
    short8 rv0 = *(const short8*)(vt_g + vbase + (long)sr * SEQ + sc * 8);
    short8 rv1 = *(const short8*)(vt_g + vbase + (long)sr * SEQ + 32 + sc * 8);
    *(short8*)&kl[0][sr * 72 + sc * 8]      = rk0;
    *(short8*)&kl[0][sr * 72 + 32 + sc * 8] = rk1;
    *(short8*)&vl[0][sr * 72 + sc * 8]      = rv0;
    *(short8*)&vl[0][sr * 72 + 32 + sc * 8] = rv1;
    __syncthreads();

#pragma unroll 1
    for (int t = 0; t < 16; ++t) {
        const int cb = t & 1;
        if (t < 15) {                  // prefetch t+1; latency hides under compute
            const long kn = base + (long)((t + 1) * 64 + sr) * HD;
            rk0 = *(const short8*)(k + kn + sc * 8);
            rk1 = *(const short8*)(k + kn + 32 + sc * 8);
            const long vn = vbase + (long)sr * SEQ + (t + 1) * 64;
            rv0 = *(const short8*)(vt_g + vn + sc * 8);
            rv1 = *(const short8*)(vt_g + vn + 32 + sc * 8);
        }

        const unsigned long long mk = mask64[b * 16 + t];
        const unsigned bit0 = (unsigned)(mk >> l31) & 1u;
        const unsigned bit1 = (unsigned)(mk >> (32 + l31)) & 1u;
        const short8 paB0 = __builtin_bit_cast(short8,
            (int4v){(hi == 0 && !bit0) ? (int)(unsigned)NEGW : 0, 0, 0, 0});
        const short8 paB1 = __builtin_bit_cast(short8,
            (int4v){(hi == 0 && !bit1) ? (int)(unsigned)NEGW : 0, 0, 0, 0});

        // S^T = K . (C2·Q)^T + rank-1 mask bias (zc = hoisted zero C-in)
        f32x16 s0 = mfma32(paB0, vfB, zc);
        f32x16 s1 = mfma32(paB1, vfB, zc);
#pragma unroll
        for (int s4 = 0; s4 < 4; ++s4) {
            const short8 kf0 = *(const short8*)&kl[cb][l31 * 72 + s4 * 16 + hi * 8];
            const short8 kf1 = *(const short8*)&kl[cb][(32 + l31) * 72 + s4 * 16 + hi * 8];
            s0 = mfma32(kf0, qf[s4], s0);
            s1 = mfma32(kf1, qf[s4], s1);
        }

        // fused exp + pack + PV + Σp — p = exp2(s) via raw v_exp_f32
#pragma unroll
        for (int kt = 0; kt < 2; ++kt) {
            const f32x16* sp = kt ? &s1 : &s0;
#pragma unroll
            for (int ks = 0; ks < 2; ++ks) {
                float p[8];
#pragma unroll
                for (int e = 0; e < 8; ++e)
                    p[e] = __builtin_amdgcn_exp2f((*sp)[8 * ks + e]);
                unsigned w0 = cvt_pk_bf16(p[0], p[1]);
                unsigned w1 = cvt_pk_bf16(p[2], p[3]);
                unsigned w2 = cvt_pk_bf16(p[4], p[5]);
                unsigned w3 = cvt_pk_bf16(p[6], p[7]);
                asm volatile("v_permlane32_swap_b32 %0, %1" : "+v"(w0), "+v"(w2));
                asm volatile("v_permlane32_swap_b32 %0, %1" : "+v"(w1), "+v"(w3));
                const short8 pa = __builtin_bit_cast(short8,
                    (int4v){(int)w0, (int)w1, (int)w2, (int)w3});
                const int koff = kt * 32 + ks * 16 + hi * 8;
                const short8 vf0 = *(const short8*)&vl[cb][l31 * 72 + koff];
                const short8 vf1 = *(const short8*)&vl[cb][(32 + l31) * 72 + koff];
                oacc0 = mfma32(pa, vf0, oacc0);
                oacc1 = mfma32(pa, vf1, oacc1);
                oaccS = mfma32(pa, vfS, oaccS);   // row-sum column
            }
        }

        if (t < 15) {                  // write NEXT tile into other buffer
            *(short8*)&kl[cb ^ 1][sr * 72 + sc * 8]      = rk0;
            *(short8*)&kl[cb ^ 1][sr * 72 + 32 + sc * 8] = rk1;
            *(short8*)&vl[cb ^ 1][sr * 72 + sc * 8]      = rv0;
            *(short8*)&vl[cb ^ 1][sr * 72 + 32 + sc * 8] = rv1;
        }
        __syncthreads();               // single barrier per tile
    }

    // epilogue: O[q][d] * rcp(Σp)
#pragma unroll
    for (int g = 0; g < 4; ++g)
#pragma unroll
        for (int j = 0; j < 4; ++j) {
            const int idx = g * 4 + j;
            const float lv = __builtin_amdgcn_rcpf(oaccS[idx]);
            const int qg = qt * 128 + w * 32 + g * 8 + j + 4 * hi;
            const long oaddr = ((long)(b * SEQ + qg)) * DIM + h * HD;
            o[oaddr + l31]      = __float2bfloat16(oacc0[idx] * lv);
            o[oaddr + 32 + l31] = __float2bfloat16(oacc1[idx] * lv);
        }
}

// ---------------------------------------------------------------------------
extern "C" void kernel_launch(void* const* d_in, const int* in_sizes, int n_in,
                              void* d_out, int out_size, void* d_ws, size_t ws_size,
                              hipStream_t stream)
{
    (void)in_sizes; (void)n_in; (void)out_size; (void)ws_size;
    const void* x    = d_in[0];
    const void* mask = d_in[1];
    const void* Wqkv = d_in[2];
    const void* Wout = d_in[3];
    const void* bout = d_in[4];
    float* out = (float*)d_out;

    const size_t nX    = (size_t)BATCH * SEQ * DIM;
    const size_t nWqkv = (size_t)3 * DIM * DIM;
    const size_t nWout = (size_t)DIM * DIM;
    const size_t nBout = DIM;
    const size_t per   = (size_t)BATCH * NHEAD * SEQ * HD;

    char* wp = (char*)d_ws;
    u16* xb    = (u16*)wp;                      wp += nX * 2;   // reused as ab
    u16* Wqkvb = (u16*)wp;                      wp += nWqkv * 2;
    u16* Woutb = (u16*)wp;                      wp += nWout * 2;
    u16* boutb = (u16*)wp;                      wp += nBout * 2;
    unsigned long long* m64 = (unsigned long long*)wp; wp += BATCH * 16 * 8;
    u16* qb    = (u16*)wp;                      wp += per * 2;
    u16* kb    = (u16*)wp;                      wp += per * 2;
    u16* vb    = (u16*)wp;                      wp += per * 2;

    // fused detect + convert + mask expansion (one launch)
    prep_all<<<3081, 256, 0, stream>>>(x, mask, Wqkv, Wout, bout,
                                       xb, Wqkvb, Woutb, boutb, m64);

    // qkv = x @ Wqkv^T : M=8192 (tiles 128), N=3072 (tiles 256) -> 768 blocks
    gemm_bt<0><<<dim3(64, 12), 256, 0, stream>>>(xb, Wqkvb,
        (bf16*)qb, (bf16*)kb, (bf16*)vb, nullptr, nullptr);
    // attention -> ab (reuses xb region)
    bf16* ab = (bf16*)xb;
    attn_fwd<<<dim3(BATCH * NHEAD * 8), 256, 0, stream>>>(
        (const bf16*)qb, (const bf16*)kb, (const bf16*)vb, m64, ab);
    // out = attn @ Wout^T + bout : M=8192, N=1024 (f32 out) -> 256 blocks
    gemm_bt<1><<<dim3(64, 4), 256, 0, stream>>>((const u16*)ab, Woutb,
        nullptr, nullptr, nullptr, out, boutb);
}

// Round 17
// 168.243 us; speedup vs baseline: 1.0508x; 1.0508x over previous
//
#include <hip/hip_runtime.h>
#include <hip/hip_bf16.h>
#include <stdint.h>

typedef __hip_bfloat16 bf16;
typedef unsigned short u16;
typedef __attribute__((ext_vector_type(8))) short short8;
typedef __attribute__((ext_vector_type(4))) float f32x4;
typedef __attribute__((ext_vector_type(16))) float f32x16;
typedef __attribute__((ext_vector_type(4))) int int4v;

#define BATCH 8
#define SEQ   1024
#define DIM   1024
#define NHEAD 16
#define HD    64
#define SCALE 0.03125f               // DIM^-0.5 = 1/32 (exact)
#define C2    0.04508422f            // SCALE * log2(e)

static __device__ __forceinline__ f32x4 mfma_bf16(short8 a, short8 b, f32x4 c) {
    return __builtin_amdgcn_mfma_f32_16x16x32_bf16(a, b, c, 0, 0, 0);
}
static __device__ __forceinline__ f32x16 mfma32(short8 a, short8 b, f32x16 c) {
    return __builtin_amdgcn_mfma_f32_32x32x16_bf16(a, b, c, 0, 0, 0);
}
static __device__ __forceinline__ unsigned cvt_pk_bf16(float lo, float hi) {
    unsigned r;
    asm("v_cvt_pk_bf16_f32 %0, %1, %2" : "=v"(r) : "v"(lo), "v"(hi));
    return r;
}
// async global->LDS, 16B per lane; LDS dest = wave-uniform base + lane*16
static __device__ __forceinline__ void gload16(const u16* g, u16* l) {
    __builtin_amdgcn_global_load_lds(
        (const __attribute__((address_space(1))) void*)g,
        (__attribute__((address_space(3))) void*)l, 16, 0, 0);
}

// ---------------------------------------------------------------------------
// Fused preprocessing: dtype detect + conversions + mask expansion, 1 launch.
// ---------------------------------------------------------------------------
static __device__ __forceinline__ void conv_seg(const void* src, u16* dst,
                                                int total, int bloc, int bcnt,
                                                bool f32in)
{
    for (int i = bloc * 256 + (int)threadIdx.x; i < total; i += bcnt * 256) {
        if (f32in) {
            const float4 a = ((const float4*)src)[2 * i];
            const float4 b = ((const float4*)src)[2 * i + 1];
            short8 o;
            o[0] = (short)__builtin_bit_cast(u16, __float2bfloat16(a.x));
            o[1] = (short)__builtin_bit_cast(u16, __float2bfloat16(a.y));
            o[2] = (short)__builtin_bit_cast(u16, __float2bfloat16(a.z));
            o[3] = (short)__builtin_bit_cast(u16, __float2bfloat16(a.w));
            o[4] = (short)__builtin_bit_cast(u16, __float2bfloat16(b.x));
            o[5] = (short)__builtin_bit_cast(u16, __float2bfloat16(b.y));
            o[6] = (short)__builtin_bit_cast(u16, __float2bfloat16(b.z));
            o[7] = (short)__builtin_bit_cast(u16, __float2bfloat16(b.w));
            ((short8*)dst)[i] = o;
        } else {
            ((short8*)dst)[i] = ((const short8*)src)[i];
        }
    }
}

__global__ __launch_bounds__(256)
void prep_all(const void* __restrict__ x, const void* __restrict__ mask,
              const void* __restrict__ wq, const void* __restrict__ wo,
              const void* __restrict__ bo,
              u16* __restrict__ xb, u16* __restrict__ wqb,
              u16* __restrict__ wob, u16* __restrict__ bob,
              unsigned long long* __restrict__ mask64)
{
    __shared__ int s_cnt[2];
    if (threadIdx.x == 0) { s_cnt[0] = 0; s_cnt[1] = 0; }
    __syncthreads();
    {
        const uint32_t wx = ((const uint32_t*)x)[threadIdx.x];
        const int e = (int)((wx >> 7) & 0xFFu);
        if (e >= 96 && e <= 159) atomicAdd(&s_cnt[0], 1);
        const uint32_t wm = ((const uint32_t*)mask)[threadIdx.x];
        if (wm > 1u) atomicAdd(&s_cnt[1], 1);
    }
    __syncthreads();
    const bool f32in = (s_cnt[0] < 192);
    const bool mbyte = (s_cnt[1] > 0);

    const int bid = blockIdx.x;
    if (bid < 2048)       conv_seg(x,  xb,  1048576, bid,        2048, f32in);
    else if (bid < 2816)  conv_seg(wq, wqb, 393216,  bid - 2048,  768, f32in);
    else if (bid < 3072)  conv_seg(wo, wob, 131072,  bid - 2816,  256, f32in);
    else if (bid == 3072) conv_seg(bo, bob, 128,     0,             1, f32in);
    else {
        const int b = bid - 3073;          // 0..7
#pragma unroll
        for (int c = 0; c < 4; ++c) {
            const int i = c * 256 + (int)threadIdx.x;
            int v;
            if (i == 0) v = 1;
            else if (mbyte) v = (int)((const uint8_t*)mask)[b * (SEQ - 1) + i - 1];
            else            v = ((const int*)mask)[b * (SEQ - 1) + i - 1];
            v = v ? 1 : 0;
            const unsigned long long bal = __ballot(v);
            if ((i & 63) == 0) mask64[b * 16 + (i >> 6)] = bal;
        }
    }
}

// ---------------------------------------------------------------------------
// GEMM: C = A @ B^T, K=1024, bf16. Round-17: block 256x128, 8 waves (4Mx2N),
// wave-tile 64x64 (r11-proven acc[4][4] + phase body, identical MFMA order).
// BK=64, 4 phases/tile. TRIPLE-buffered LDS (3 x 48KB = 144KB): tile kt
// stages kt+2 (issued ~2 tiles ahead of its drain -> HBM latency fully
// hidden); tile-end drain is COUNTED vmcnt(6) (this tile's stages stay in
// flight across the barrier, T4). 1 block/CU x 8 waves = 2 waves/SIMD.
// Source-side XOR swizzle identical to round-11 (0 conflicts measured).
// EPI 0: scatter q(xC2)/k/v^T.  EPI 1: C + bias -> f32.
// ---------------------------------------------------------------------------
template<int EPI>
__global__ __launch_bounds__(512, 1)
void gemm_bt(const u16* __restrict__ A, const u16* __restrict__ Bm,
             bf16* __restrict__ o0, bf16* __restrict__ o1, bf16* __restrict__ o2,
             float* __restrict__ fo, const u16* __restrict__ bias)
{
    constexpr int K   = 1024;
    constexpr int NT  = K / 64;          // 16 K-tiles
    constexpr int BUF = 384 * 64;        // u16 per buffer (48KB)
    __shared__ u16 lds[3 * BUF];         // 144KB

    const int tid  = threadIdx.x;
    const int lane = tid & 63;
    const int w    = tid >> 6;           // 0..7
    const int wr   = w >> 1, wc = w & 1; // 4M x 2N waves, wave = 64x64
    const int l15  = lane & 15, l4 = lane >> 4;

    const long atile = (long)blockIdx.x * 256;
    const long btile = (long)blockIdx.y * 128;

    // staging: 48 chunks of 8 rows x 64 cols; wave w owns chunks 6w..6w+5.
    // lane -> row chunk*8 + (lane>>3), LDS slot lane&7, global col-chunk
    // (lane&7)^(lane>>3)   [LDS[r][s] = G[r][s^(r&7)]]
    const int rl  = lane >> 3;
    const int gs8 = ((lane & 7) ^ rl) * 8;
    const u16* gp[6];
#pragma unroll
    for (int j = 0; j < 6; ++j) {
        const int g = 6 * w + j;
        const int r = g * 8 + rl;        // combined row: [0,256)=A, [256,384)=B
        gp[j] = (r < 256) ? A  + (atile + r) * (long)K + gs8
                          : Bm + (btile + (r - 256)) * (long)K + gs8;
    }

    // read map (round-11 proven): slot = ((kk^b2)*4 + (l4^(l15&3)))*8
    const int lx  = l4 ^ (l15 & 3);
    const int b2  = (l15 >> 2) & 1;
    const int sl0 = (b2 * 4 + lx) * 8;          // kk=0
    const int sl1 = (((1 ^ b2) * 4) + lx) * 8;  // kk=1
    const int ar  = wr * 64 + l15;              // + mt*16  (A rows 0..255)
    const int br  = 256 + wc * 64 + l15;        // + nt*16  (B rows 256..383)

    f32x4 acc[4][4];
    const f32x4 fz = {0.f, 0.f, 0.f, 0.f};
#pragma unroll
    for (int i = 0; i < 4; ++i)
#pragma unroll
        for (int j = 0; j < 4; ++j) acc[i][j] = fz;

#define STG(bufo, kt, j) gload16(gp[j] + (size_t)(kt) * 64, \
                                 &lds[(bufo) + (6 * w + (j)) * 512])

    // prologue: stage tiles 0 and 1; drain tile 0 only (counted)
#pragma unroll
    for (int j = 0; j < 6; ++j) STG(0, 0, j);
#pragma unroll
    for (int j = 0; j < 6; ++j) STG(BUF, 1, j);
    asm volatile("s_waitcnt vmcnt(6)" ::: "memory");
    __builtin_amdgcn_s_barrier();
    __builtin_amdgcn_sched_barrier(0);

#pragma unroll 1
    for (int kt = 0; kt < NT; ++kt) {
        const int co = (kt % 3) * BUF;
        const int so = ((kt + 2) % 3) * BUF;     // stage target (never read now)
        const bool st = (kt + 2 < NT);
        short8 bfr[2][4], af0, af1;

        // ---- phase 0: all B-frags + A mt=0; stage j=0,1 ----
#pragma unroll
        for (int nt = 0; nt < 4; ++nt) {
            bfr[0][nt] = *(const short8*)&lds[co + (br + nt * 16) * 64 + sl0];
            bfr[1][nt] = *(const short8*)&lds[co + (br + nt * 16) * 64 + sl1];
        }
        af0 = *(const short8*)&lds[co + ar * 64 + sl0];
        af1 = *(const short8*)&lds[co + ar * 64 + sl1];
        if (st) { STG(so, kt + 2, 0); STG(so, kt + 2, 1); }
        asm volatile("s_waitcnt lgkmcnt(0)" ::: "memory");
        __builtin_amdgcn_sched_barrier(0);           // rule #18 fence
        __builtin_amdgcn_s_setprio(1);
#pragma unroll
        for (int nt = 0; nt < 4; ++nt) {
            acc[0][nt] = mfma_bf16(af0, bfr[0][nt], acc[0][nt]);
            acc[0][nt] = mfma_bf16(af1, bfr[1][nt], acc[0][nt]);
        }
        __builtin_amdgcn_s_setprio(0);

        // ---- phases 1..3: A mt; stages j=2,3 (p1) and j=4,5 (p2) ----
#pragma unroll
        for (int mt = 1; mt < 4; ++mt) {
            af0 = *(const short8*)&lds[co + (ar + mt * 16) * 64 + sl0];
            af1 = *(const short8*)&lds[co + (ar + mt * 16) * 64 + sl1];
            if (st && mt < 3) { STG(so, kt + 2, 2 * mt); STG(so, kt + 2, 2 * mt + 1); }
            asm volatile("s_waitcnt lgkmcnt(0)" ::: "memory");
            __builtin_amdgcn_sched_barrier(0);
            __builtin_amdgcn_s_setprio(1);
#pragma unroll
            for (int nt = 0; nt < 4; ++nt) {
                acc[mt][nt] = mfma_bf16(af0, bfr[0][nt], acc[mt][nt]);
                acc[mt][nt] = mfma_bf16(af1, bfr[1][nt], acc[mt][nt]);
            }
            __builtin_amdgcn_s_setprio(0);
        }

        // tile end: counted drain — this tile's 6 stages stay in flight
        if (st) asm volatile("s_waitcnt vmcnt(6)" ::: "memory");
        else    asm volatile("s_waitcnt vmcnt(0)" ::: "memory");
        __builtin_amdgcn_s_barrier();
        __builtin_amdgcn_sched_barrier(0);
    }
#undef STG

    // epilogue: C/D layout col = lane&15, row = (lane>>4)*4 + r  [m89/m91]
    const long ci0 = atile + wr * 64;
    const int  cj0 = (int)btile + wc * 64;
#pragma unroll
    for (int mt = 0; mt < 4; ++mt) {
#pragma unroll
        for (int nt = 0; nt < 4; ++nt) {
            const int j = cj0 + nt * 16 + l15;
#pragma unroll
            for (int r = 0; r < 4; ++r) {
                const long i = ci0 + mt * 16 + l4 * 4 + r;
                float vv = acc[mt][nt][r];
                if (EPI == 0) {
                    const int which = j >> 10;         // 0=q 1=k 2=v
                    const int h     = (j >> 6) & 15;
                    const int dd    = j & 63;
                    const long b    = i >> 10;
                    const long n    = i & 1023;
                    const long bhh  = b * NHEAD + h;
                    if (which == 0)  // Q pre-scaled by C2 (softmax fold)
                        o0[(bhh * SEQ + n) * HD + dd] = __float2bfloat16(vv * C2);
                    else if (which == 1)
                        o1[(bhh * SEQ + n) * HD + dd] = __float2bfloat16(vv);
                    else // V stored transposed: [bh][d][n]
                        o2[(bhh * HD + dd) * SEQ + n] = __float2bfloat16(vv);
                } else {
                    const u16 bw = bias[j];
                    vv += __bfloat162float(__builtin_bit_cast(bf16, bw));
                    fo[i * DIM + j] = vv;
                }
            }
        }
    }
}

// ---------------------------------------------------------------------------
// Flash attention, swapped-operand 32x32 form (unchanged from round 15).
// ---------------------------------------------------------------------------
__global__ __launch_bounds__(256)
void attn_fwd(const bf16* __restrict__ q, const bf16* __restrict__ k,
              const bf16* __restrict__ vt_g,
              const unsigned long long* __restrict__ mask64,
              bf16* __restrict__ o)
{
    __shared__ u16 kl[2][64 * 72];     // K tile  [k in tile][d], +8 pad
    __shared__ u16 vl[2][64 * 72];     // V^T tile [d][k in tile], +8 pad

    const int tid  = threadIdx.x;
    const int lane = tid & 63;
    const int w    = tid >> 6;
    const int l31  = lane & 31;
    const int hi   = lane >> 5;
    const int bh   = blockIdx.x >> 3;
    const int qt   = blockIdx.x & 7;
    const int b    = bh >> 4;
    const int h    = bh & 15;

    const long base  = (long)bh * SEQ * HD;   // q,k: [bh][n][64]
    const long vbase = (long)bh * HD * SEQ;   // v^T: [bh][d][1024]

    const int qrow = qt * 128 + w * 32 + l31;
    const int mi   = (int)((mask64[b * 16 + (qrow >> 6)] >> (qrow & 63)) & 1ull);

    short8 qf[4];
#pragma unroll
    for (int s4 = 0; s4 < 4; ++s4)
        qf[s4] = *(const short8*)(q + base + (long)qrow * HD + s4 * 16 + hi * 8);
    if (!mi) {                         // dead q-row: zero Q -> s == 0
#pragma unroll
        for (int s4 = 0; s4 < 4; ++s4)
            qf[s4] = __builtin_bit_cast(short8, (int4v){0, 0, 0, 0});
    }

    f32x16 oacc0, oacc1, oaccS, zc;
#pragma unroll
    for (int i = 0; i < 16; ++i)
        { oacc0[i] = 0.f; oacc1[i] = 0.f; oaccS[i] = 0.f; zc[i] = 0.f; }

    const u16 NEGW = __builtin_bit_cast(u16, __float2bfloat16(-1e30f));
    const short8 vfB = __builtin_bit_cast(short8,  // bias gate: mi(q) at kk=0
        (int4v){(hi == 0 && mi) ? 0x3F80 : 0, 0, 0, 0});
    const short8 vfS = __builtin_bit_cast(short8,  // all-ones column (row sum)
        (int4v){0x3F803F80, 0x3F803F80, 0x3F803F80, 0x3F803F80});

    const int sr = tid >> 2, sc = tid & 3;
    short8 rk0 = *(const short8*)(k + base + (long)sr * HD + sc * 8);
    short8 rk1 = *(const short8*)(k + base + (long)sr * HD + 32 + sc * 8);
    short8 rv0 = *(const short8*)(vt_g + vbase + (long)sr * SEQ + sc * 8);
    short8 rv1 = *(const short8*)(vt_g + vbase + (long)sr * SEQ + 32 + sc * 8);
    *(short8*)&kl[0][sr * 72 + sc * 8]      = rk0;
    *(short8*)&kl[0][sr * 72 + 32 + sc * 8] = rk1;
    *(short8*)&vl[0][sr * 72 + sc * 8]      = rv0;
    *(short8*)&vl[0][sr * 72 + 32 + sc * 8] = rv1;
    __syncthreads();

#pragma unroll 1
    for (int t = 0; t < 16; ++t) {
        const int cb = t & 1;
        if (t < 15) {                  // prefetch t+1; latency hides under compute
            const long kn = base + (long)((t + 1) * 64 + sr) * HD;
            rk0 = *(const short8*)(k + kn + sc * 8);
            rk1 = *(const short8*)(k + kn + 32 + sc * 8);
            const long vn = vbase + (long)sr * SEQ + (t + 1) * 64;
            rv0 = *(const short8*)(vt_g + vn + sc * 8);
            rv1 = *(const short8*)(vt_g + vn + 32 + sc * 8);
        }

        const unsigned long long mk = mask64[b * 16 + t];
        const unsigned bit0 = (unsigned)(mk >> l31) & 1u;
        const unsigned bit1 = (unsigned)(mk >> (32 + l31)) & 1u;
        const short8 paB0 = __builtin_bit_cast(short8,
            (int4v){(hi == 0 && !bit0) ? (int)(unsigned)NEGW : 0, 0, 0, 0});
        const short8 paB1 = __builtin_bit_cast(short8,
            (int4v){(hi == 0 && !bit1) ? (int)(unsigned)NEGW : 0, 0, 0, 0});

        // S^T = K . (C2·Q)^T + rank-1 mask bias (zc = hoisted zero C-in)
        f32x16 s0 = mfma32(paB0, vfB, zc);
        f32x16 s1 = mfma32(paB1, vfB, zc);
#pragma unroll
        for (int s4 = 0; s4 < 4; ++s4) {
            const short8 kf0 = *(const short8*)&kl[cb][l31 * 72 + s4 * 16 + hi * 8];
            const short8 kf1 = *(const short8*)&kl[cb][(32 + l31) * 72 + s4 * 16 + hi * 8];
            s0 = mfma32(kf0, qf[s4], s0);
            s1 = mfma32(kf1, qf[s4], s1);
        }

        // fused exp + pack + PV + Σp — p = exp2(s) via raw v_exp_f32
#pragma unroll
        for (int kt = 0; kt < 2; ++kt) {
            const f32x16* sp = kt ? &s1 : &s0;
#pragma unroll
            for (int ks = 0; ks < 2; ++ks) {
                float p[8];
#pragma unroll
                for (int e = 0; e < 8; ++e)
                    p[e] = __builtin_amdgcn_exp2f((*sp)[8 * ks + e]);
                unsigned w0 = cvt_pk_bf16(p[0], p[1]);
                unsigned w1 = cvt_pk_bf16(p[2], p[3]);
                unsigned w2 = cvt_pk_bf16(p[4], p[5]);
                unsigned w3 = cvt_pk_bf16(p[6], p[7]);
                asm volatile("v_permlane32_swap_b32 %0, %1" : "+v"(w0), "+v"(w2));
                asm volatile("v_permlane32_swap_b32 %0, %1" : "+v"(w1), "+v"(w3));
                const short8 pa = __builtin_bit_cast(short8,
                    (int4v){(int)w0, (int)w1, (int)w2, (int)w3});
                const int koff = kt * 32 + ks * 16 + hi * 8;
                const short8 vf0 = *(const short8*)&vl[cb][l31 * 72 + koff];
                const short8 vf1 = *(const short8*)&vl[cb][(32 + l31) * 72 + koff];
                oacc0 = mfma32(pa, vf0, oacc0);
                oacc1 = mfma32(pa, vf1, oacc1);
                oaccS = mfma32(pa, vfS, oaccS);   // row-sum column
            }
        }

        if (t < 15) {                  // write NEXT tile into other buffer
            *(short8*)&kl[cb ^ 1][sr * 72 + sc * 8]      = rk0;
            *(short8*)&kl[cb ^ 1][sr * 72 + 32 + sc * 8] = rk1;
            *(short8*)&vl[cb ^ 1][sr * 72 + sc * 8]      = rv0;
            *(short8*)&vl[cb ^ 1][sr * 72 + 32 + sc * 8] = rv1;
        }
        __syncthreads();               // single barrier per tile
    }

    // epilogue: O[q][d] * rcp(Σp)
#pragma unroll
    for (int g = 0; g < 4; ++g)
#pragma unroll
        for (int j = 0; j < 4; ++j) {
            const int idx = g * 4 + j;
            const float lv = __builtin_amdgcn_rcpf(oaccS[idx]);
            const int qg = qt * 128 + w * 32 + g * 8 + j + 4 * hi;
            const long oaddr = ((long)(b * SEQ + qg)) * DIM + h * HD;
            o[oaddr + l31]      = __float2bfloat16(oacc0[idx] * lv);
            o[oaddr + 32 + l31] = __float2bfloat16(oacc1[idx] * lv);
        }
}

// ---------------------------------------------------------------------------
extern "C" void kernel_launch(void* const* d_in, const int* in_sizes, int n_in,
                              void* d_out, int out_size, void* d_ws, size_t ws_size,
                              hipStream_t stream)
{
    (void)in_sizes; (void)n_in; (void)out_size; (void)ws_size;
    const void* x    = d_in[0];
    const void* mask = d_in[1];
    const void* Wqkv = d_in[2];
    const void* Wout = d_in[3];
    const void* bout = d_in[4];
    float* out = (float*)d_out;

    const size_t nX    = (size_t)BATCH * SEQ * DIM;
    const size_t nWqkv = (size_t)3 * DIM * DIM;
    const size_t nWout = (size_t)DIM * DIM;
    const size_t nBout = DIM;
    const size_t per   = (size_t)BATCH * NHEAD * SEQ * HD;

    char* wp = (char*)d_ws;
    u16* xb    = (u16*)wp;                      wp += nX * 2;   // reused as ab
    u16* Wqkvb = (u16*)wp;                      wp += nWqkv * 2;
    u16* Woutb = (u16*)wp;                      wp += nWout * 2;
    u16* boutb = (u16*)wp;                      wp += nBout * 2;
    unsigned long long* m64 = (unsigned long long*)wp; wp += BATCH * 16 * 8;
    u16* qb    = (u16*)wp;                      wp += per * 2;
    u16* kb    = (u16*)wp;                      wp += per * 2;
    u16* vb    = (u16*)wp;                      wp += per * 2;

    // fused detect + convert + mask expansion (one launch)
    prep_all<<<3081, 256, 0, stream>>>(x, mask, Wqkv, Wout, bout,
                                       xb, Wqkvb, Woutb, boutb, m64);

    // qkv = x @ Wqkv^T : M=8192 (tiles 256), N=3072 (tiles 128) -> 768 blocks
    gemm_bt<0><<<dim3(32, 24), 512, 0, stream>>>(xb, Wqkvb,
        (bf16*)qb, (bf16*)kb, (bf16*)vb, nullptr, nullptr);
    // attention -> ab (reuses xb region)
    bf16* ab = (bf16*)xb;
    attn_fwd<<<dim3(BATCH * NHEAD * 8), 256, 0, stream>>>(
        (const bf16*)qb, (const bf16*)kb, (const bf16*)vb, m64, ab);
    // out = attn @ Wout^T + bout : M=8192 (tiles 256), N=1024 -> 256 blocks
    gemm_bt<1><<<dim3(32, 8), 512, 0, stream>>>((const u16*)ab, Woutb,
        nullptr, nullptr, nullptr, out, boutb);
}

// Round 18
// 156.571 us; speedup vs baseline: 1.1292x; 1.0745x over previous
//
#include <hip/hip_runtime.h>
#include <hip/hip_bf16.h>
#include <stdint.h>

typedef __hip_bfloat16 bf16;
typedef unsigned short u16;
typedef __attribute__((ext_vector_type(8))) short short8;
typedef __attribute__((ext_vector_type(4))) float f32x4;
typedef __attribute__((ext_vector_type(16))) float f32x16;
typedef __attribute__((ext_vector_type(4))) int int4v;

#define BATCH 8
#define SEQ   1024
#define DIM   1024
#define NHEAD 16
#define HD    64
#define SCALE 0.03125f               // DIM^-0.5 = 1/32 (exact)
#define C2    0.04508422f            // SCALE * log2(e)

static __device__ __forceinline__ f32x4 mfma_bf16(short8 a, short8 b, f32x4 c) {
    return __builtin_amdgcn_mfma_f32_16x16x32_bf16(a, b, c, 0, 0, 0);
}
static __device__ __forceinline__ f32x16 mfma32(short8 a, short8 b, f32x16 c) {
    return __builtin_amdgcn_mfma_f32_32x32x16_bf16(a, b, c, 0, 0, 0);
}
static __device__ __forceinline__ unsigned cvt_pk_bf16(float lo, float hi) {
    unsigned r;
    asm("v_cvt_pk_bf16_f32 %0, %1, %2" : "=v"(r) : "v"(lo), "v"(hi));
    return r;
}
// async global->LDS, 16B per lane; LDS dest = wave-uniform base + lane*16
static __device__ __forceinline__ void gload16(const u16* g, u16* l) {
    __builtin_amdgcn_global_load_lds(
        (const __attribute__((address_space(1))) void*)g,
        (__attribute__((address_space(3))) void*)l, 16, 0, 0);
}

// ---------------------------------------------------------------------------
// Fused preprocessing: dtype detect + conversions + mask expansion, 1 launch.
// ---------------------------------------------------------------------------
static __device__ __forceinline__ void conv_seg(const void* src, u16* dst,
                                                int total, int bloc, int bcnt,
                                                bool f32in)
{
    for (int i = bloc * 256 + (int)threadIdx.x; i < total; i += bcnt * 256) {
        if (f32in) {
            const float4 a = ((const float4*)src)[2 * i];
            const float4 b = ((const float4*)src)[2 * i + 1];
            short8 o;
            o[0] = (short)__builtin_bit_cast(u16, __float2bfloat16(a.x));
            o[1] = (short)__builtin_bit_cast(u16, __float2bfloat16(a.y));
            o[2] = (short)__builtin_bit_cast(u16, __float2bfloat16(a.z));
            o[3] = (short)__builtin_bit_cast(u16, __float2bfloat16(a.w));
            o[4] = (short)__builtin_bit_cast(u16, __float2bfloat16(b.x));
            o[5] = (short)__builtin_bit_cast(u16, __float2bfloat16(b.y));
            o[6] = (short)__builtin_bit_cast(u16, __float2bfloat16(b.z));
            o[7] = (short)__builtin_bit_cast(u16, __float2bfloat16(b.w));
            ((short8*)dst)[i] = o;
        } else {
            ((short8*)dst)[i] = ((const short8*)src)[i];
        }
    }
}

__global__ __launch_bounds__(256)
void prep_all(const void* __restrict__ x, const void* __restrict__ mask,
              const void* __restrict__ wq, const void* __restrict__ wo,
              const void* __restrict__ bo,
              u16* __restrict__ xb, u16* __restrict__ wqb,
              u16* __restrict__ wob, u16* __restrict__ bob,
              unsigned long long* __restrict__ mask64)
{
    __shared__ int s_cnt[2];
    if (threadIdx.x == 0) { s_cnt[0] = 0; s_cnt[1] = 0; }
    __syncthreads();
    {
        const uint32_t wx = ((const uint32_t*)x)[threadIdx.x];
        const int e = (int)((wx >> 7) & 0xFFu);
        if (e >= 96 && e <= 159) atomicAdd(&s_cnt[0], 1);
        const uint32_t wm = ((const uint32_t*)mask)[threadIdx.x];
        if (wm > 1u) atomicAdd(&s_cnt[1], 1);
    }
    __syncthreads();
    const bool f32in = (s_cnt[0] < 192);
    const bool mbyte = (s_cnt[1] > 0);

    const int bid = blockIdx.x;
    if (bid < 2048)       conv_seg(x,  xb,  1048576, bid,        2048, f32in);
    else if (bid < 2816)  conv_seg(wq, wqb, 393216,  bid - 2048,  768, f32in);
    else if (bid < 3072)  conv_seg(wo, wob, 131072,  bid - 2816,  256, f32in);
    else if (bid == 3072) conv_seg(bo, bob, 128,     0,             1, f32in);
    else {
        const int b = bid - 3073;          // 0..7
#pragma unroll
        for (int c = 0; c < 4; ++c) {
            const int i = c * 256 + (int)threadIdx.x;
            int v;
            if (i == 0) v = 1;
            else if (mbyte) v = (int)((const uint8_t*)mask)[b * (SEQ - 1) + i - 1];
            else            v = ((const int*)mask)[b * (SEQ - 1) + i - 1];
            v = v ? 1 : 0;
            const unsigned long long bal = __ballot(v);
            if ((i & 63) == 0) mask64[b * 16 + (i >> 6)] = bal;
        }
    }
}

// ---------------------------------------------------------------------------
// GEMM: C = A @ B^T, K=1024, bf16. 128x128 tile, 4 waves (2x2), BK=64.
// 4-phase interleaved K-tile (T3), ONE barrier per K-tile. (round-11/15
// proven optimum for this shape; r16/r17 geometry variants regressed.)
// EPI 0: Q pre-scaled by C2; V stored transposed.  EPI 1: C + bias -> f32.
// ---------------------------------------------------------------------------
template<int EPI>
__global__ __launch_bounds__(256)
void gemm_bt(const u16* __restrict__ A, const u16* __restrict__ Bm,
             bf16* __restrict__ o0, bf16* __restrict__ o1, bf16* __restrict__ o2,
             float* __restrict__ fo, const u16* __restrict__ bias)
{
    constexpr int K   = 1024;
    constexpr int NT  = K / 64;          // 16 K-tiles
    constexpr int BUF = 256 * 64;        // u16 per buffer (32KB)
    __shared__ u16 lds[2 * BUF];         // 64KB total

    const int tid  = threadIdx.x;
    const int lane = tid & 63;
    const int w    = tid >> 6;           // 0..3
    const int wr   = w >> 1, wc = w & 1;
    const int l15  = lane & 15, l4 = lane >> 4;

    const long atile = (long)blockIdx.x * 128;
    const long btile = (long)blockIdx.y * 128;

    const int rl  = lane >> 3;
    const int gs8 = ((lane & 7) ^ rl) * 8;
    const u16* gp[8];
#pragma unroll
    for (int j = 0; j < 8; ++j) {
        const int g = 8 * w + j;
        const int r = g * 8 + rl;        // combined row: [0,128)=A, [128,256)=B
        gp[j] = (r < 128) ? A  + (atile + r) * (long)K + gs8
                          : Bm + (btile + (r - 128)) * (long)K + gs8;
    }

    const int lx  = l4 ^ (l15 & 3);
    const int b2  = (l15 >> 2) & 1;
    const int sl0 = (b2 * 4 + lx) * 8;          // kk=0
    const int sl1 = (((1 ^ b2) * 4) + lx) * 8;  // kk=1
    const int arow = wr * 64 + l15;
    const int brow = 128 + wc * 64 + l15;

    f32x4 acc[4][4];
    const f32x4 fz = {0.f, 0.f, 0.f, 0.f};
#pragma unroll
    for (int i = 0; i < 4; ++i)
#pragma unroll
        for (int j = 0; j < 4; ++j) acc[i][j] = fz;

#define STG(bufo, kt, j) gload16(gp[j] + (size_t)(kt) * 64, \
                                 &lds[(bufo) + (8 * w + (j)) * 512])

#pragma unroll
    for (int j = 0; j < 8; ++j) STG(0, 0, j);
    asm volatile("s_waitcnt vmcnt(0)" ::: "memory");
    __builtin_amdgcn_s_barrier();
    __builtin_amdgcn_sched_barrier(0);

    int cur = 0;
#pragma unroll 1
    for (int kt = 0; kt < NT; ++kt) {
        const int co = cur * BUF;
        const int no = (cur ^ 1) * BUF;
        short8 bfr[2][4], af0, af1;

#pragma unroll
        for (int nt = 0; nt < 4; ++nt) {
            bfr[0][nt] = *(const short8*)&lds[co + (brow + nt * 16) * 64 + sl0];
            bfr[1][nt] = *(const short8*)&lds[co + (brow + nt * 16) * 64 + sl1];
        }
        af0 = *(const short8*)&lds[co + arow * 64 + sl0];
        af1 = *(const short8*)&lds[co + arow * 64 + sl1];
        if (kt + 1 < NT) {
            STG(no, kt + 1, 0); STG(no, kt + 1, 1);
            STG(no, kt + 1, 2); STG(no, kt + 1, 3);
        }
        asm volatile("s_waitcnt lgkmcnt(0)" ::: "memory");
        __builtin_amdgcn_sched_barrier(0);           // rule #18 fence
        __builtin_amdgcn_s_setprio(1);
#pragma unroll
        for (int nt = 0; nt < 4; ++nt) {
            acc[0][nt] = mfma_bf16(af0, bfr[0][nt], acc[0][nt]);
            acc[0][nt] = mfma_bf16(af1, bfr[1][nt], acc[0][nt]);
        }
        __builtin_amdgcn_s_setprio(0);

#pragma unroll
        for (int mt = 1; mt < 4; ++mt) {
            af0 = *(const short8*)&lds[co + (arow + mt * 16) * 64 + sl0];
            af1 = *(const short8*)&lds[co + (arow + mt * 16) * 64 + sl1];
            if (mt == 1 && kt + 1 < NT) {
                STG(no, kt + 1, 4); STG(no, kt + 1, 5);
                STG(no, kt + 1, 6); STG(no, kt + 1, 7);
            }
            asm volatile("s_waitcnt lgkmcnt(0)" ::: "memory");
            __builtin_amdgcn_sched_barrier(0);
            __builtin_amdgcn_s_setprio(1);
#pragma unroll
            for (int nt = 0; nt < 4; ++nt) {
                acc[mt][nt] = mfma_bf16(af0, bfr[0][nt], acc[mt][nt]);
                acc[mt][nt] = mfma_bf16(af1, bfr[1][nt], acc[mt][nt]);
            }
            __builtin_amdgcn_s_setprio(0);
        }

        asm volatile("s_waitcnt vmcnt(0)" ::: "memory");
        __builtin_amdgcn_s_barrier();
        __builtin_amdgcn_sched_barrier(0);
        cur ^= 1;
    }
#undef STG

    const long ci0 = atile + wr * 64;
    const int  cj0 = (int)btile + wc * 64;
#pragma unroll
    for (int mt = 0; mt < 4; ++mt) {
#pragma unroll
        for (int nt = 0; nt < 4; ++nt) {
            const int j = cj0 + nt * 16 + l15;
#pragma unroll
            for (int r = 0; r < 4; ++r) {
                const long i = ci0 + mt * 16 + l4 * 4 + r;
                float vv = acc[mt][nt][r];
                if (EPI == 0) {
                    const int which = j >> 10;         // 0=q 1=k 2=v
                    const int h     = (j >> 6) & 15;
                    const int dd    = j & 63;
                    const long b    = i >> 10;
                    const long n    = i & 1023;
                    const long bhh  = b * NHEAD + h;
                    if (which == 0)  // Q pre-scaled by C2 (softmax fold)
                        o0[(bhh * SEQ + n) * HD + dd] = __float2bfloat16(vv * C2);
                    else if (which == 1)
                        o1[(bhh * SEQ + n) * HD + dd] = __float2bfloat16(vv);
                    else // V stored transposed: [bh][d][n]
                        o2[(bhh * HD + dd) * SEQ + n] = __float2bfloat16(vv);
                } else {
                    const u16 bw = bias[j];
                    vv += __bfloat162float(__builtin_bit_cast(bf16, bw));
                    fo[i * DIM + j] = vv;
                }
            }
        }
    }
}

// ---------------------------------------------------------------------------
// Flash attention, swapped-operand 32x32 form. Round-18: XCD-aware block
// swizzle (T1): all 8 q-tile blocks of one (b,h) land on the SAME XCD
// (linear = ((bh>>3)*8 + qt)*8 + (bh&7); ids differ by 8 ≡ 0 mod 8), so the
// 256KB K/V panel is fetched once per XCD instead of 8x. Compute unchanged.
// ---------------------------------------------------------------------------
__global__ __launch_bounds__(256)
void attn_fwd(const bf16* __restrict__ q, const bf16* __restrict__ k,
              const bf16* __restrict__ vt_g,
              const unsigned long long* __restrict__ mask64,
              bf16* __restrict__ o)
{
    __shared__ u16 kl[2][64 * 72];     // K tile  [k in tile][d], +8 pad
    __shared__ u16 vl[2][64 * 72];     // V^T tile [d][k in tile], +8 pad

    const int tid  = threadIdx.x;
    const int lane = tid & 63;
    const int w    = tid >> 6;
    const int l31  = lane & 31;
    const int hi   = lane >> 5;
    const int lin  = blockIdx.x;       // XCD swizzle: same-bh -> same XCD
    const int bh   = ((lin >> 6) << 3) | (lin & 7);
    const int qt   = (lin >> 3) & 7;
    const int b    = bh >> 4;
    const int h    = bh & 15;

    const long base  = (long)bh * SEQ * HD;   // q,k: [bh][n][64]
    const long vbase = (long)bh * HD * SEQ;   // v^T: [bh][d][1024]

    const int qrow = qt * 128 + w * 32 + l31;
    const int mi   = (int)((mask64[b * 16 + (qrow >> 6)] >> (qrow & 63)) & 1ull);

    short8 qf[4];
#pragma unroll
    for (int s4 = 0; s4 < 4; ++s4)
        qf[s4] = *(const short8*)(q + base + (long)qrow * HD + s4 * 16 + hi * 8);
    if (!mi) {                         // dead q-row: zero Q -> s == 0
#pragma unroll
        for (int s4 = 0; s4 < 4; ++s4)
            qf[s4] = __builtin_bit_cast(short8, (int4v){0, 0, 0, 0});
    }

    f32x16 oacc0, oacc1, oaccS, zc;
#pragma unroll
    for (int i = 0; i < 16; ++i)
        { oacc0[i] = 0.f; oacc1[i] = 0.f; oaccS[i] = 0.f; zc[i] = 0.f; }

    const u16 NEGW = __builtin_bit_cast(u16, __float2bfloat16(-1e30f));
    const short8 vfB = __builtin_bit_cast(short8,  // bias gate: mi(q) at kk=0
        (int4v){(hi == 0 && mi) ? 0x3F80 : 0, 0, 0, 0});
    const short8 vfS = __builtin_bit_cast(short8,  // all-ones column (row sum)
        (int4v){0x3F803F80, 0x3F803F80, 0x3F803F80, 0x3F803F80});

    const int sr = tid >> 2, sc = tid & 3;
    short8 rk0 = *(const short8*)(k + base + (long)sr * HD + sc * 8);
    short8 rk1 = *(const short8*)(k + base + (long)sr * HD + 32 + sc * 8);
    short8 rv0 = *(const short8*)(vt_g + vbase + (long)sr * SEQ + sc * 8);
    short8 rv1 = *(const short8*)(vt_g + vbase + (long)sr * SEQ + 32 + sc * 8);
    *(short8*)&kl[0][sr * 72 + sc * 8]      = rk0;
    *(short8*)&kl[0][sr * 72 + 32 + sc * 8] = rk1;
    *(short8*)&vl[0][sr * 72 + sc * 8]      = rv0;
    *(short8*)&vl[0][sr * 72 + 32 + sc * 8] = rv1;
    __syncthreads();

#pragma unroll 1
    for (int t = 0; t < 16; ++t) {
        const int cb = t & 1;
        if (t < 15) {                  // prefetch t+1; latency hides under compute
            const long kn = base + (long)((t + 1) * 64 + sr) * HD;
            rk0 = *(const short8*)(k + kn + sc * 8);
            rk1 = *(const short8*)(k + kn + 32 + sc * 8);
            const long vn = vbase + (long)sr * SEQ + (t + 1) * 64;
            rv0 = *(const short8*)(vt_g + vn + sc * 8);
            rv1 = *(const short8*)(vt_g + vn + 32 + sc * 8);
        }

        const unsigned long long mk = mask64[b * 16 + t];
        const unsigned bit0 = (unsigned)(mk >> l31) & 1u;
        const unsigned bit1 = (unsigned)(mk >> (32 + l31)) & 1u;
        const short8 paB0 = __builtin_bit_cast(short8,
            (int4v){(hi == 0 && !bit0) ? (int)(unsigned)NEGW : 0, 0, 0, 0});
        const short8 paB1 = __builtin_bit_cast(short8,
            (int4v){(hi == 0 && !bit1) ? (int)(unsigned)NEGW : 0, 0, 0, 0});

        // S^T = K . (C2·Q)^T + rank-1 mask bias (zc = hoisted zero C-in)
        f32x16 s0 = mfma32(paB0, vfB, zc);
        f32x16 s1 = mfma32(paB1, vfB, zc);
#pragma unroll
        for (int s4 = 0; s4 < 4; ++s4) {
            const short8 kf0 = *(const short8*)&kl[cb][l31 * 72 + s4 * 16 + hi * 8];
            const short8 kf1 = *(const short8*)&kl[cb][(32 + l31) * 72 + s4 * 16 + hi * 8];
            s0 = mfma32(kf0, qf[s4], s0);
            s1 = mfma32(kf1, qf[s4], s1);
        }

        // fused exp + pack + PV + Σp — p = exp2(s) via raw v_exp_f32
#pragma unroll
        for (int kt = 0; kt < 2; ++kt) {
            const f32x16* sp = kt ? &s1 : &s0;
#pragma unroll
            for (int ks = 0; ks < 2; ++ks) {
                float p[8];
#pragma unroll
                for (int e = 0; e < 8; ++e)
                    p[e] = __builtin_amdgcn_exp2f((*sp)[8 * ks + e]);
                unsigned w0 = cvt_pk_bf16(p[0], p[1]);
                unsigned w1 = cvt_pk_bf16(p[2], p[3]);
                unsigned w2 = cvt_pk_bf16(p[4], p[5]);
                unsigned w3 = cvt_pk_bf16(p[6], p[7]);
                asm volatile("v_permlane32_swap_b32 %0, %1" : "+v"(w0), "+v"(w2));
                asm volatile("v_permlane32_swap_b32 %0, %1" : "+v"(w1), "+v"(w3));
                const short8 pa = __builtin_bit_cast(short8,
                    (int4v){(int)w0, (int)w1, (int)w2, (int)w3});
                const int koff = kt * 32 + ks * 16 + hi * 8;
                const short8 vf0 = *(const short8*)&vl[cb][l31 * 72 + koff];
                const short8 vf1 = *(const short8*)&vl[cb][(32 + l31) * 72 + koff];
                oacc0 = mfma32(pa, vf0, oacc0);
                oacc1 = mfma32(pa, vf1, oacc1);
                oaccS = mfma32(pa, vfS, oaccS);   // row-sum column
            }
        }

        if (t < 15) {                  // write NEXT tile into other buffer
            *(short8*)&kl[cb ^ 1][sr * 72 + sc * 8]      = rk0;
            *(short8*)&kl[cb ^ 1][sr * 72 + 32 + sc * 8] = rk1;
            *(short8*)&vl[cb ^ 1][sr * 72 + sc * 8]      = rv0;
            *(short8*)&vl[cb ^ 1][sr * 72 + 32 + sc * 8] = rv1;
        }
        __syncthreads();               // single barrier per tile
    }

    // epilogue: O[q][d] * rcp(Σp)
#pragma unroll
    for (int g = 0; g < 4; ++g)
#pragma unroll
        for (int j = 0; j < 4; ++j) {
            const int idx = g * 4 + j;
            const float lv = __builtin_amdgcn_rcpf(oaccS[idx]);
            const int qg = qt * 128 + w * 32 + g * 8 + j + 4 * hi;
            const long oaddr = ((long)(b * SEQ + qg)) * DIM + h * HD;
            o[oaddr + l31]      = __float2bfloat16(oacc0[idx] * lv);
            o[oaddr + 32 + l31] = __float2bfloat16(oacc1[idx] * lv);
        }
}

// ---------------------------------------------------------------------------
extern "C" void kernel_launch(void* const* d_in, const int* in_sizes, int n_in,
                              void* d_out, int out_size, void* d_ws, size_t ws_size,
                              hipStream_t stream)
{
    (void)in_sizes; (void)n_in; (void)out_size; (void)ws_size;
    const void* x    = d_in[0];
    const void* mask = d_in[1];
    const void* Wqkv = d_in[2];
    const void* Wout = d_in[3];
    const void* bout = d_in[4];
    float* out = (float*)d_out;

    const size_t nX    = (size_t)BATCH * SEQ * DIM;
    const size_t nWqkv = (size_t)3 * DIM * DIM;
    const size_t nWout = (size_t)DIM * DIM;
    const size_t nBout = DIM;
    const size_t per   = (size_t)BATCH * NHEAD * SEQ * HD;

    char* wp = (char*)d_ws;
    u16* xb    = (u16*)wp;                      wp += nX * 2;   // reused as ab
    u16* Wqkvb = (u16*)wp;                      wp += nWqkv * 2;
    u16* Woutb = (u16*)wp;                      wp += nWout * 2;
    u16* boutb = (u16*)wp;                      wp += nBout * 2;
    unsigned long long* m64 = (unsigned long long*)wp; wp += BATCH * 16 * 8;
    u16* qb    = (u16*)wp;                      wp += per * 2;
    u16* kb    = (u16*)wp;                      wp += per * 2;
    u16* vb    = (u16*)wp;                      wp += per * 2;

    // fused detect + convert + mask expansion (one launch)
    prep_all<<<3081, 256, 0, stream>>>(x, mask, Wqkv, Wout, bout,
                                       xb, Wqkvb, Woutb, boutb, m64);

    // qkv = x @ Wqkv^T : M=8192, N=3072 (V scattered transposed, Q pre-scaled)
    gemm_bt<0><<<dim3(64, 24), 256, 0, stream>>>(xb, Wqkvb,
        (bf16*)qb, (bf16*)kb, (bf16*)vb, nullptr, nullptr);
    // attention -> ab (reuses xb region); XCD-swizzled block order
    bf16* ab = (bf16*)xb;
    attn_fwd<<<dim3(BATCH * NHEAD * 8), 256, 0, stream>>>(
        (const bf16*)qb, (const bf16*)kb, (const bf16*)vb, m64, ab);
    // out = attn @ Wout^T + bout : M=8192, N=1024 (f32 out)
    gemm_bt<1><<<dim3(64, 8), 256, 0, stream>>>((const u16*)ab, Woutb,
        nullptr, nullptr, nullptr, out, boutb);
}